// Round 4
// baseline (85.357 us; speedup 1.0000x reference)
//
#include <hip/hip_runtime.h>
#include <hip/hip_bf16.h>
#include <stdint.h>

typedef __bf16 bf16;
typedef __attribute__((ext_vector_type(8))) __bf16 bf16x8;
typedef __attribute__((ext_vector_type(4))) float f32x4;

#define GLOAD16(gsrc, ldst)                                              \
  __builtin_amdgcn_global_load_lds(                                      \
      (const __attribute__((address_space(1))) unsigned int*)(gsrc),     \
      (__attribute__((address_space(3))) unsigned int*)(ldst), 16, 0, 0)

static constexpr int T_LEN = 4096;
static constexpr int WIN = 16;
static constexpr int WSZ = 2 * WIN + 1;  // 33

__device__ __forceinline__ bf16x8 cvt8(float4 a, float4 b) {
  bf16x8 o;
  o[0] = (bf16)a.x; o[1] = (bf16)a.y; o[2] = (bf16)a.z; o[3] = (bf16)a.w;
  o[4] = (bf16)b.x; o[5] = (bf16)b.y; o[6] = (bf16)b.z; o[7] = (bf16)b.w;
  return o;
}

// quad-butterfly add via DPP (pure VALU, no DS pipe).
// 0xB1 = quad_perm [1,0,3,2] (xor 1); 0x4E = quad_perm [2,3,0,1] (xor 2)
__device__ __forceinline__ float quad_reduce_add(float x) {
  int xi = __builtin_bit_cast(int, x);
  int y1 = __builtin_amdgcn_mov_dpp(xi, 0xB1, 0xF, 0xF, true);
  x = x + __builtin_bit_cast(float, y1);
  int x2 = __builtin_bit_cast(int, x);
  int y2 = __builtin_amdgcn_mov_dpp(x2, 0x4E, 0xF, 0xF, true);
  return x + __builtin_bit_cast(float, y2);
}

// ---- cast x (fp32 -> bf16), 8 elems/thread, 8192*512 total ----
__global__ __launch_bounds__(256) void cast_x_kernel(const float* __restrict__ x,
                                                     bf16* __restrict__ xb) {
  int i = blockIdx.x * 256 + threadIdx.x;  // 524288 threads
  const float4* s4 = (const float4*)x + (size_t)i * 2;
  ((bf16x8*)xb)[i] = cvt8(s4[0], s4[1]);
}

// ---- cast + pack Wq,Wk,Wv -> wqkv[1536][512], Wp -> wpb[512][512] ----
__global__ __launch_bounds__(256) void cast_w_kernel(const float* __restrict__ wq,
                                                     const float* __restrict__ wk,
                                                     const float* __restrict__ wv,
                                                     const float* __restrict__ wp,
                                                     bf16* __restrict__ wqkv,
                                                     bf16* __restrict__ wpb) {
  int i = blockIdx.x * 256 + threadIdx.x;  // 131072 threads (4 * 512*512/8)
  int which = i >> 15;                     // 32768 groups of 8 per matrix
  int j = i & 32767;
  const float* src = (which == 0) ? wq : (which == 1) ? wk : (which == 2) ? wv : wp;
  bf16* dst = (which < 3) ? (wqkv + (size_t)which * 512 * 512) : wpb;
  const float4* s4 = (const float4*)src + (size_t)j * 2;
  ((bf16x8*)dst)[j] = cvt8(s4[0], s4[1]);
}

// ---- GEMM: C[m][n] = sum_k A[m][k] * Bw[n][k]  (A: Mx512 bf16, Bw: Nx512 bf16 row-major)
// EPI=0: store bf16 into Cb with leading dim ldc
// EPI=1: store fp32 Cf[m*512+n] = acc + Xres[m*512+n]   (residual)
template <int EPI>
__global__ __launch_bounds__(256) void gemm_bt_kernel(const bf16* __restrict__ A,
                                                      const bf16* __restrict__ Bw,
                                                      bf16* __restrict__ Cb, int ldc,
                                                      float* __restrict__ Cf,
                                                      const float* __restrict__ Xres,
                                                      int NB) {
  constexpr int K = 512, BK = 32;
  __shared__ __align__(16) bf16 As[128 * BK];
  __shared__ __align__(16) bf16 Bs[128 * BK];
  const int tid = threadIdx.x;
  const int l = tid & 63;
  const int w = tid >> 6;
  const int m0 = (blockIdx.x / NB) * 128;
  const int n0 = (blockIdx.x % NB) * 128;
  const int arow = tid >> 2;
  const int acol = (tid & 3) * 8;
  const bf16* Ag = A + (size_t)(m0 + arow) * K + acol;
  const bf16* Bg = Bw + (size_t)(n0 + arow) * K + acol;

  const f32x4 zero = {0.f, 0.f, 0.f, 0.f};
  f32x4 acc[4][4];
#pragma unroll
  for (int i = 0; i < 4; ++i)
#pragma unroll
    for (int j = 0; j < 4; ++j) acc[i][j] = zero;

  const int wm = (w >> 1) * 64;
  const int wn = (w & 1) * 64;
  const int frow = l & 15;
  const int fcol = (l >> 4) * 8;

  for (int k0 = 0; k0 < K; k0 += BK) {
    GLOAD16(Ag + k0,           &As[tid * 8]);
    GLOAD16(Ag + 64 * K + k0,  &As[tid * 8 + 2048]);
    GLOAD16(Bg + k0,           &Bs[tid * 8]);
    GLOAD16(Bg + 64 * K + k0,  &Bs[tid * 8 + 2048]);
    __syncthreads();
    bf16x8 af[4], bfr[4];
#pragma unroll
    for (int mi = 0; mi < 4; ++mi)
      af[mi] = *(const bf16x8*)&As[(wm + mi * 16 + frow) * BK + fcol];
#pragma unroll
    for (int ni = 0; ni < 4; ++ni)
      bfr[ni] = *(const bf16x8*)&Bs[(wn + ni * 16 + frow) * BK + fcol];
#pragma unroll
    for (int mi = 0; mi < 4; ++mi)
#pragma unroll
      for (int ni = 0; ni < 4; ++ni)
        acc[mi][ni] = __builtin_amdgcn_mfma_f32_16x16x32_bf16(af[mi], bfr[ni], acc[mi][ni], 0, 0, 0);
    __syncthreads();
  }

  // C/D layout: col = lane&15, row = (lane>>4)*4 + reg
  const int r0 = (l >> 4) * 4;
  const int c0 = l & 15;
#pragma unroll
  for (int mi = 0; mi < 4; ++mi) {
#pragma unroll
    for (int ni = 0; ni < 4; ++ni) {
      int row = m0 + wm + mi * 16 + r0;
      int col = n0 + wn + ni * 16 + c0;
#pragma unroll
      for (int r = 0; r < 4; ++r) {
        if (EPI == 0) {
          Cb[(size_t)(row + r) * ldc + col] = (bf16)acc[mi][ni][r];
        } else {
          size_t o = (size_t)(row + r) * 512 + col;
          Cf[o] = acc[mi][ni][r] + Xres[o];
        }
      }
    }
  }
}

// ---- local attention, LDS-tiled ----
// Block = 256 threads: one (b,h) x 64 t-rows. K,V staged in LDS (bf16,
// 96 positions x 64 dims, row stride 72 to balance banks).
// Thread = (row r = tid>>2, 16-dim slice ds = tid&3).
static constexpr int TC = 64;       // t-rows per block
static constexpr int NPOS = 96;     // TC + 2*WIN halo
static constexpr int KSTRIDE = 72;  // padded LDS row stride (bf16 elems)

__global__ __launch_bounds__(256) void attn_kernel(const bf16* __restrict__ qkv,
                                                   bf16* __restrict__ aout) {
  __shared__ __align__(16) bf16 Kh[NPOS * KSTRIDE];
  __shared__ __align__(16) bf16 Vh[NPOS * KSTRIDE];

  const int tid = threadIdx.x;
  const int bid = blockIdx.x;          // 1024 = 2 * 8 * 64
  const int chunk = bid & 63;
  const int h = (bid >> 6) & 7;
  const int b = bid >> 9;
  const int t0 = chunk * TC;
  const int base = b * T_LEN;

  const int r = tid >> 2;        // row within chunk [0,64)
  const int ds = tid & 3;        // 16-dim slice
  const int t = t0 + r;

  // Q slice -> 16 f32 regs (load before staging so it overlaps)
  const bf16* qrow = qkv + (size_t)(base + t) * 1536 + h * 64 + ds * 16;
  bf16x8 qa = ((const bf16x8*)qrow)[0];
  bf16x8 qb = ((const bf16x8*)qrow)[1];

  // ---- stage K,V: 96 positions x 64 dims, clamped ----
  for (int c = tid; c < NPOS * 8; c += 256) {  // 768 chunks of 8 bf16
    int p = c >> 3;
    int d8 = (c & 7) * 8;
    int pg = min(max(t0 - WIN + p, 0), T_LEN - 1);
    const bf16* kr = qkv + (size_t)(base + pg) * 1536 + 512 + h * 64 + d8;
    const bf16* vr = qkv + (size_t)(base + pg) * 1536 + 1024 + h * 64 + d8;
    *(bf16x8*)&Kh[p * KSTRIDE + d8] = *(const bf16x8*)kr;
    *(bf16x8*)&Vh[p * KSTRIDE + d8] = *(const bf16x8*)vr;
  }

  float qf[16];
#pragma unroll
  for (int e = 0; e < 8; ++e) { qf[e] = (float)qa[e]; qf[8 + e] = (float)qb[e]; }
  const float scale = 0.125f;    // 64^-0.5

  __syncthreads();

  // ---- scores (DPP quad butterfly reduce; 4 independent partials) ----
  float s[WSZ];
#pragma unroll
  for (int w = 0; w < WSZ; ++w) {
    const bf16* kp = &Kh[(r + w) * KSTRIDE + ds * 16];
    bf16x8 ka = ((const bf16x8*)kp)[0];
    bf16x8 kb = ((const bf16x8*)kp)[1];
    float a0 = 0.f, a1 = 0.f, a2 = 0.f, a3 = 0.f;
#pragma unroll
    for (int e = 0; e < 4; ++e) {
      a0 += qf[e]      * (float)ka[e];
      a1 += qf[4 + e]  * (float)ka[4 + e];
      a2 += qf[8 + e]  * (float)kb[e];
      a3 += qf[12 + e] * (float)kb[4 + e];
    }
    float acc = (a0 + a1) + (a2 + a3);
    acc = quad_reduce_add(acc);
    int pos = t - WIN + w;
    bool valid = (pos >= 0) && (pos < T_LEN);
    s[w] = valid ? acc * scale : -1e30f;
  }

  // ---- softmax over 33 (tree reductions) ----
  float tm[16];
#pragma unroll
  for (int i = 0; i < 16; ++i) tm[i] = fmaxf(s[i], s[i + 16]);
#pragma unroll
  for (int i = 0; i < 8; ++i) tm[i] = fmaxf(tm[i], tm[i + 8]);
#pragma unroll
  for (int i = 0; i < 4; ++i) tm[i] = fmaxf(tm[i], tm[i + 4]);
  float m = fmaxf(fmaxf(fmaxf(tm[0], tm[1]), fmaxf(tm[2], tm[3])), s[32]);

#pragma unroll
  for (int w = 0; w < WSZ; ++w) s[w] = __expf(s[w] - m);

  float ts[16];
#pragma unroll
  for (int i = 0; i < 16; ++i) ts[i] = s[i] + s[i + 16];
#pragma unroll
  for (int i = 0; i < 8; ++i) ts[i] = ts[i] + ts[i + 8];
#pragma unroll
  for (int i = 0; i < 4; ++i) ts[i] = ts[i] + ts[i + 4];
  float sum = ((ts[0] + ts[1]) + (ts[2] + ts[3])) + s[32];
  float inv = 1.f / sum;

  // ---- PV ----
  float o[16];
#pragma unroll
  for (int e = 0; e < 16; ++e) o[e] = 0.f;
#pragma unroll
  for (int w = 0; w < WSZ; ++w) {
    const bf16* vp = &Vh[(r + w) * KSTRIDE + ds * 16];
    bf16x8 va = ((const bf16x8*)vp)[0];
    bf16x8 vb = ((const bf16x8*)vp)[1];
    float pw = s[w];
#pragma unroll
    for (int e = 0; e < 8; ++e) o[e] += pw * (float)va[e];
#pragma unroll
    for (int e = 0; e < 8; ++e) o[8 + e] += pw * (float)vb[e];
  }

  bf16x8 o0, o1;
#pragma unroll
  for (int e = 0; e < 8; ++e) {
    o0[e] = (bf16)(o[e] * inv);
    o1[e] = (bf16)(o[8 + e] * inv);
  }
  bf16* orow = aout + (size_t)(base + t) * 512 + h * 64 + ds * 16;
  ((bf16x8*)orow)[0] = o0;
  ((bf16x8*)orow)[1] = o1;
}

// ---- in-place LayerNorm, one wave per 512-wide row ----
__global__ __launch_bounds__(256) void ln_kernel(float* __restrict__ y,
                                                 const float* __restrict__ gamma,
                                                 const float* __restrict__ beta) {
  const int tid = threadIdx.x;
  const int l = tid & 63;
  const int row = blockIdx.x * 4 + (tid >> 6);
  float* p = y + (size_t)row * 512 + l * 8;
  float4 a = *(const float4*)(p);
  float4 b = *(const float4*)(p + 4);
  float s = a.x + a.y + a.z + a.w + b.x + b.y + b.z + b.w;
  float ss = a.x * a.x + a.y * a.y + a.z * a.z + a.w * a.w +
             b.x * b.x + b.y * b.y + b.z * b.z + b.w * b.w;
#pragma unroll
  for (int off = 32; off > 0; off >>= 1) {
    s += __shfl_xor(s, off);
    ss += __shfl_xor(ss, off);
  }
  float mu = s * (1.f / 512.f);
  float var = ss * (1.f / 512.f) - mu * mu;
  float rs = rsqrtf(var + 1e-5f);
  float4 g0 = *(const float4*)(gamma + l * 8);
  float4 g1 = *(const float4*)(gamma + l * 8 + 4);
  float4 b0 = *(const float4*)(beta + l * 8);
  float4 b1 = *(const float4*)(beta + l * 8 + 4);
  float4 o0, o1;
  o0.x = g0.x * (a.x - mu) * rs + b0.x;
  o0.y = g0.y * (a.y - mu) * rs + b0.y;
  o0.z = g0.z * (a.z - mu) * rs + b0.z;
  o0.w = g0.w * (a.w - mu) * rs + b0.w;
  o1.x = g1.x * (b.x - mu) * rs + b1.x;
  o1.y = g1.y * (b.y - mu) * rs + b1.y;
  o1.z = g1.z * (b.z - mu) * rs + b1.z;
  o1.w = g1.w * (b.w - mu) * rs + b1.w;
  *(float4*)(p) = o0;
  *(float4*)(p + 4) = o1;
}

extern "C" void kernel_launch(void* const* d_in, const int* in_sizes, int n_in,
                              void* d_out, int out_size, void* d_ws, size_t ws_size,
                              hipStream_t stream) {
  const float* x  = (const float*)d_in[0];
  const float* Wq = (const float*)d_in[1];
  const float* Wk = (const float*)d_in[2];
  const float* Wv = (const float*)d_in[3];
  const float* Wp = (const float*)d_in[4];
  const float* g  = (const float*)d_in[5];
  const float* be = (const float*)d_in[6];
  float* out = (float*)d_out;

  char* ws = (char*)d_ws;
  bf16* xb   = (bf16*)(ws);                                   // 8,388,608 B
  bf16* wqkv = (bf16*)(ws + 8388608);                         // 1,572,864 B
  bf16* wpb  = (bf16*)(ws + 8388608 + 1572864);               //   524,288 B
  bf16* qkv  = (bf16*)(ws + 8388608 + 1572864 + 524288);      // 25,165,824 B
  bf16* aout = (bf16*)(ws + 8388608 + 1572864 + 524288 + 25165824);  // 8,388,608 B

  cast_x_kernel<<<2048, 256, 0, stream>>>(x, xb);
  cast_w_kernel<<<512, 256, 0, stream>>>(Wq, Wk, Wv, Wp, wqkv, wpb);
  // QKV: M=8192, N=1536 -> 64 x 12 tiles
  gemm_bt_kernel<0><<<64 * 12, 256, 0, stream>>>(xb, wqkv, qkv, 1536, nullptr, nullptr, 12);
  // attn: blocks = B(2) * H(8) * T/TC(64) = 1024
  attn_kernel<<<1024, 256, 0, stream>>>(qkv, aout);
  // proj + residual: M=8192, N=512 -> 64 x 4 tiles
  gemm_bt_kernel<1><<<64 * 4, 256, 0, stream>>>(aout, wpb, nullptr, 0, out, x, 4);
  ln_kernel<<<2048, 256, 0, stream>>>(out, g, be);
}

// Round 5
// 66.687 us; speedup vs baseline: 1.2800x; 1.2800x over previous
//
#include <hip/hip_runtime.h>
#include <hip/hip_bf16.h>
#include <stdint.h>

typedef __bf16 bf16;
typedef __attribute__((ext_vector_type(8))) __bf16 bf16x8;
typedef __attribute__((ext_vector_type(2))) __bf16 bf16x2;
typedef __attribute__((ext_vector_type(4))) float f32x4;
typedef __attribute__((ext_vector_type(4))) unsigned int u32x4;

#define GLOAD16(gsrc, ldst)                                              \
  __builtin_amdgcn_global_load_lds(                                      \
      (const __attribute__((address_space(1))) unsigned int*)(gsrc),     \
      (__attribute__((address_space(3))) unsigned int*)(ldst), 16, 0, 0)

static constexpr int T_LEN = 4096;
static constexpr int WIN = 16;

__device__ __forceinline__ bf16x8 cvt8(float4 a, float4 b) {
  bf16x8 o;
  o[0] = (bf16)a.x; o[1] = (bf16)a.y; o[2] = (bf16)a.z; o[3] = (bf16)a.w;
  o[4] = (bf16)b.x; o[5] = (bf16)b.y; o[6] = (bf16)b.z; o[7] = (bf16)b.w;
  return o;
}

// ---- cast x (fp32 -> bf16), 8 elems/thread, 8192*512 total ----
__global__ __launch_bounds__(256) void cast_x_kernel(const float* __restrict__ x,
                                                     bf16* __restrict__ xb) {
  int i = blockIdx.x * 256 + threadIdx.x;  // 524288 threads
  const float4* s4 = (const float4*)x + (size_t)i * 2;
  ((bf16x8*)xb)[i] = cvt8(s4[0], s4[1]);
}

// ---- cast + pack Wq,Wk,Wv -> wqkv[1536][512], Wp -> wpb[512][512] ----
__global__ __launch_bounds__(256) void cast_w_kernel(const float* __restrict__ wq,
                                                     const float* __restrict__ wk,
                                                     const float* __restrict__ wv,
                                                     const float* __restrict__ wp,
                                                     bf16* __restrict__ wqkv,
                                                     bf16* __restrict__ wpb) {
  int i = blockIdx.x * 256 + threadIdx.x;  // 131072 threads (4 * 512*512/8)
  int which = i >> 15;                     // 32768 groups of 8 per matrix
  int j = i & 32767;
  const float* src = (which == 0) ? wq : (which == 1) ? wk : (which == 2) ? wv : wp;
  bf16* dst = (which < 3) ? (wqkv + (size_t)which * 512 * 512) : wpb;
  const float4* s4 = (const float4*)src + (size_t)j * 2;
  ((bf16x8*)dst)[j] = cvt8(s4[0], s4[1]);
}

// ---- GEMM: C[m][n] = sum_k A[m][k] * Bw[n][k]  (A: Mx512 bf16, Bw: Nx512 bf16 row-major)
// EPI=0: store bf16 into Cb with leading dim ldc
// EPI=1: store fp32 Cf[m*512+n] = acc + Xres[m*512+n]   (residual)
template <int EPI>
__global__ __launch_bounds__(256) void gemm_bt_kernel(const bf16* __restrict__ A,
                                                      const bf16* __restrict__ Bw,
                                                      bf16* __restrict__ Cb, int ldc,
                                                      float* __restrict__ Cf,
                                                      const float* __restrict__ Xres,
                                                      int NB) {
  constexpr int K = 512, BK = 32;
  __shared__ __align__(16) bf16 As[128 * BK];
  __shared__ __align__(16) bf16 Bs[128 * BK];
  const int tid = threadIdx.x;
  const int l = tid & 63;
  const int w = tid >> 6;
  const int m0 = (blockIdx.x / NB) * 128;
  const int n0 = (blockIdx.x % NB) * 128;
  const int arow = tid >> 2;
  const int acol = (tid & 3) * 8;
  const bf16* Ag = A + (size_t)(m0 + arow) * K + acol;
  const bf16* Bg = Bw + (size_t)(n0 + arow) * K + acol;

  const f32x4 zero = {0.f, 0.f, 0.f, 0.f};
  f32x4 acc[4][4];
#pragma unroll
  for (int i = 0; i < 4; ++i)
#pragma unroll
    for (int j = 0; j < 4; ++j) acc[i][j] = zero;

  const int wm = (w >> 1) * 64;
  const int wn = (w & 1) * 64;
  const int frow = l & 15;
  const int fcol = (l >> 4) * 8;

  for (int k0 = 0; k0 < K; k0 += BK) {
    GLOAD16(Ag + k0,           &As[tid * 8]);
    GLOAD16(Ag + 64 * K + k0,  &As[tid * 8 + 2048]);
    GLOAD16(Bg + k0,           &Bs[tid * 8]);
    GLOAD16(Bg + 64 * K + k0,  &Bs[tid * 8 + 2048]);
    __syncthreads();
    bf16x8 af[4], bfr[4];
#pragma unroll
    for (int mi = 0; mi < 4; ++mi)
      af[mi] = *(const bf16x8*)&As[(wm + mi * 16 + frow) * BK + fcol];
#pragma unroll
    for (int ni = 0; ni < 4; ++ni)
      bfr[ni] = *(const bf16x8*)&Bs[(wn + ni * 16 + frow) * BK + fcol];
#pragma unroll
    for (int mi = 0; mi < 4; ++mi)
#pragma unroll
      for (int ni = 0; ni < 4; ++ni)
        acc[mi][ni] = __builtin_amdgcn_mfma_f32_16x16x32_bf16(af[mi], bfr[ni], acc[mi][ni], 0, 0, 0);
    __syncthreads();
  }

  // C/D layout: col = lane&15, row = (lane>>4)*4 + reg
  const int r0 = (l >> 4) * 4;
  const int c0 = l & 15;
#pragma unroll
  for (int mi = 0; mi < 4; ++mi) {
#pragma unroll
    for (int ni = 0; ni < 4; ++ni) {
      int row = m0 + wm + mi * 16 + r0;
      int col = n0 + wn + ni * 16 + c0;
#pragma unroll
      for (int r = 0; r < 4; ++r) {
        if (EPI == 0) {
          Cb[(size_t)(row + r) * ldc + col] = (bf16)acc[mi][ni][r];
        } else {
          size_t o = (size_t)(row + r) * 512 + col;
          Cf[o] = acc[mi][ni][r] + Xres[o];
        }
      }
    }
  }
}

// ---- local attention, MFMA-based ----
// Block = 256 threads (4 waves), covers 64 t-rows of one (b,h).
// Stage K[96][72] (bf16, b128 writes) and V[96][74] (row-major, b32 writes).
// Wave = one 16-row group:
//   S^T[48w][16q] = mfma(K-frag, Q-frag) x6   (C: q=lane&15, w=16*wt+4*(l>>4)+reg)
//   mask/exp/sum (no max: scores ~N(0,1), self-pos keeps sum>=1), normalize,
//   pack P[16q][48w] bf16 in per-wave LDS (stride 56),
//   O[16q][64d] = mfma(P-frag, V-frag) x8  (V as B-frag via 8 u16 gathers, stride 74
//   => banks (8g + c/2) conflict-free). kh=1 g>=2: P=0, V-row clamped (finite*0=0).
static constexpr int TCB = 64;
static constexpr int NP = 96;
static constexpr int KST = 72;
static constexpr int VST = 74;

__global__ __launch_bounds__(256) void attn_kernel(const bf16* __restrict__ qkv,
                                                   bf16* __restrict__ aout) {
  __shared__ __align__(16) bf16 Kl[NP * KST];
  __shared__ __align__(16) unsigned short Vl[NP * VST];
  __shared__ __align__(16) bf16 PO[4 * 16 * 72];  // per-wave P(stride 56)/O(stride 72) overlay

  const int tid = threadIdx.x;
  const int wid = tid >> 6;
  const int l = tid & 63;
  const int g = l >> 4;
  const int c = l & 15;

  const int bid = blockIdx.x;  // 1024 = 2 * 8 * 64
  const int chunk = bid & 63;
  const int h = (bid >> 6) & 7;
  const int b = bid >> 9;
  const int t0 = chunk * TCB;
  const int base = b * T_LEN;

  // ---- stage K (row-major b128) and V (row-major b32 x4, stride 74) ----
#pragma unroll
  for (int i = 0; i < 3; ++i) {
    int task = tid + i * 256;      // 768 tasks = 96 pos x 8 col-chunks
    int p = task >> 3;
    int c8 = (task & 7) * 8;
    int pg = min(max(t0 - WIN + p, 0), T_LEN - 1);
    const bf16* kr = qkv + (size_t)(base + pg) * 1536 + 512 + h * 64 + c8;
    const bf16* vr = qkv + (size_t)(base + pg) * 1536 + 1024 + h * 64 + c8;
    *(bf16x8*)&Kl[p * KST + c8] = *(const bf16x8*)kr;
    u32x4 vv = __builtin_bit_cast(u32x4, *(const bf16x8*)vr);
    unsigned int* vp = (unsigned int*)&Vl[p * VST + c8];
    vp[0] = vv[0]; vp[1] = vv[1]; vp[2] = vv[2]; vp[3] = vv[3];
  }
  __syncthreads();

  const int tg = t0 + wid * 16;
  const float scale = 0.125f;  // 64^-0.5

  // ---- Q fragments (global direct): k-map (g,e) -> d = 32*kh + 8g + e ----
  const bf16* qrow = qkv + (size_t)(base + tg + c) * 1536 + h * 64;
  bf16x8 qf0 = *(const bf16x8*)(qrow + g * 8);
  bf16x8 qf1 = *(const bf16x8*)(qrow + 32 + g * 8);

  const f32x4 zero = {0.f, 0.f, 0.f, 0.f};
  const u32x4 zu = {0u, 0u, 0u, 0u};

  // ---- S^T = K @ Q^T : 3 w-tiles x 2 k-halves ----
  f32x4 st[3];
#pragma unroll
  for (int wt = 0; wt < 3; ++wt) {
    int rk = 16 * wid + 16 * wt + c;  // block-pos of this lane's K row
    bf16x8 ka0 = *(const bf16x8*)&Kl[rk * KST + g * 8];
    bf16x8 ka1 = *(const bf16x8*)&Kl[rk * KST + 32 + g * 8];
    f32x4 t = __builtin_amdgcn_mfma_f32_16x16x32_bf16(ka0, qf0, zero, 0, 0, 0);
    st[wt] = __builtin_amdgcn_mfma_f32_16x16x32_bf16(ka1, qf1, t, 0, 0, 0);
  }

  // ---- masked exp + row-sum (q = c; w = 16*wt + 4g + r) ----
  float pv[3][4];
  float lsum = 0.f;
#pragma unroll
  for (int wt = 0; wt < 3; ++wt) {
#pragma unroll
    for (int r = 0; r < 4; ++r) {
      int w = 16 * wt + 4 * g + r;
      int pos = tg - WIN + w;
      bool valid = (w >= c) && (w <= c + 32) && (pos >= 0) && (pos < T_LEN);
      float e = __expf(st[wt][r] * scale);
      pv[wt][r] = valid ? e : 0.f;
      lsum += pv[wt][r];
    }
  }
  lsum += __shfl_xor(lsum, 16);
  lsum += __shfl_xor(lsum, 32);
  float inv = 1.f / lsum;

  // ---- write normalized P (bf16, stride 56) ----
  bf16* P = &PO[wid * 16 * 72];
#pragma unroll
  for (int wt = 0; wt < 3; ++wt) {
    bf16x2 p01, p23;
    p01[0] = (bf16)(pv[wt][0] * inv);
    p01[1] = (bf16)(pv[wt][1] * inv);
    p23[0] = (bf16)(pv[wt][2] * inv);
    p23[1] = (bf16)(pv[wt][3] * inv);
    *(bf16x2*)&P[c * 56 + 16 * wt + 4 * g]     = p01;
    *(bf16x2*)&P[c * 56 + 16 * wt + 4 * g + 2] = p23;
  }

  // ---- PV: O[16q][64d] ----
  bf16x8 pa0 = *(const bf16x8*)&P[c * 56 + 8 * g];
  int g1 = (g < 2) ? g : 1;
  bf16x8 pa1 = *(const bf16x8*)&P[c * 56 + 32 + 8 * g1];
  if (g >= 2) pa1 = __builtin_bit_cast(bf16x8, zu);  // zero A-slots for w>=48

  f32x4 acc[4] = {zero, zero, zero, zero};
#pragma unroll
  for (int dt = 0; dt < 4; ++dt) {
    const int col = 16 * dt + c;
    // kh0: w = 8g + e  (rows 16*wid + w)
    {
      const int rb = (16 * wid + 8 * g) * VST + col;
      u32x4 u;
      u[0] = (unsigned)Vl[rb]            | ((unsigned)Vl[rb + VST]     << 16);
      u[1] = (unsigned)Vl[rb + 2 * VST]  | ((unsigned)Vl[rb + 3 * VST] << 16);
      u[2] = (unsigned)Vl[rb + 4 * VST]  | ((unsigned)Vl[rb + 5 * VST] << 16);
      u[3] = (unsigned)Vl[rb + 6 * VST]  | ((unsigned)Vl[rb + 7 * VST] << 16);
      acc[dt] = __builtin_amdgcn_mfma_f32_16x16x32_bf16(
          pa0, __builtin_bit_cast(bf16x8, u), acc[dt], 0, 0, 0);
    }
    // kh1: w = 32 + 8g + e, clamped to <=47 (P=0 there, V finite)
    {
      u32x4 u;
#pragma unroll
      for (int j = 0; j < 4; ++j) {
        int w0 = min(32 + 8 * g + 2 * j, 47);
        int w1 = min(32 + 8 * g + 2 * j + 1, 47);
        u[j] = (unsigned)Vl[(16 * wid + w0) * VST + col] |
               ((unsigned)Vl[(16 * wid + w1) * VST + col] << 16);
      }
      acc[dt] = __builtin_amdgcn_mfma_f32_16x16x32_bf16(
          pa1, __builtin_bit_cast(bf16x8, u), acc[dt], 0, 0, 0);
    }
  }

  // ---- O to LDS (stride 72), then coalesced store ----
  bf16* O = &PO[wid * 16 * 72];
#pragma unroll
  for (int dt = 0; dt < 4; ++dt)
#pragma unroll
    for (int r = 0; r < 4; ++r)
      O[(4 * g + r) * 72 + 16 * dt + c] = (bf16)acc[dt][r];

  bf16x8 o0 = *(const bf16x8*)&O[c * 72 + g * 8];
  bf16x8 o1 = *(const bf16x8*)&O[c * 72 + 32 + g * 8];
  bf16* orow = aout + (size_t)(base + tg + c) * 512 + h * 64;
  *(bf16x8*)(orow + g * 8) = o0;
  *(bf16x8*)(orow + 32 + g * 8) = o1;
}

// ---- in-place LayerNorm, one wave per 512-wide row ----
__global__ __launch_bounds__(256) void ln_kernel(float* __restrict__ y,
                                                 const float* __restrict__ gamma,
                                                 const float* __restrict__ beta) {
  const int tid = threadIdx.x;
  const int l = tid & 63;
  const int row = blockIdx.x * 4 + (tid >> 6);
  float* p = y + (size_t)row * 512 + l * 8;
  float4 a = *(const float4*)(p);
  float4 b = *(const float4*)(p + 4);
  float s = a.x + a.y + a.z + a.w + b.x + b.y + b.z + b.w;
  float ss = a.x * a.x + a.y * a.y + a.z * a.z + a.w * a.w +
             b.x * b.x + b.y * b.y + b.z * b.z + b.w * b.w;
#pragma unroll
  for (int off = 32; off > 0; off >>= 1) {
    s += __shfl_xor(s, off);
    ss += __shfl_xor(ss, off);
  }
  float mu = s * (1.f / 512.f);
  float var = ss * (1.f / 512.f) - mu * mu;
  float rs = rsqrtf(var + 1e-5f);
  float4 g0 = *(const float4*)(gamma + l * 8);
  float4 g1 = *(const float4*)(gamma + l * 8 + 4);
  float4 b0 = *(const float4*)(beta + l * 8);
  float4 b1 = *(const float4*)(beta + l * 8 + 4);
  float4 o0, o1;
  o0.x = g0.x * (a.x - mu) * rs + b0.x;
  o0.y = g0.y * (a.y - mu) * rs + b0.y;
  o0.z = g0.z * (a.z - mu) * rs + b0.z;
  o0.w = g0.w * (a.w - mu) * rs + b0.w;
  o1.x = g1.x * (b.x - mu) * rs + b1.x;
  o1.y = g1.y * (b.y - mu) * rs + b1.y;
  o1.z = g1.z * (b.z - mu) * rs + b1.z;
  o1.w = g1.w * (b.w - mu) * rs + b1.w;
  *(float4*)(p) = o0;
  *(float4*)(p + 4) = o1;
}

extern "C" void kernel_launch(void* const* d_in, const int* in_sizes, int n_in,
                              void* d_out, int out_size, void* d_ws, size_t ws_size,
                              hipStream_t stream) {
  const float* x  = (const float*)d_in[0];
  const float* Wq = (const float*)d_in[1];
  const float* Wk = (const float*)d_in[2];
  const float* Wv = (const float*)d_in[3];
  const float* Wp = (const float*)d_in[4];
  const float* g  = (const float*)d_in[5];
  const float* be = (const float*)d_in[6];
  float* out = (float*)d_out;

  char* ws = (char*)d_ws;
  bf16* xb   = (bf16*)(ws);                                   // 8,388,608 B
  bf16* wqkv = (bf16*)(ws + 8388608);                         // 1,572,864 B
  bf16* wpb  = (bf16*)(ws + 8388608 + 1572864);               //   524,288 B
  bf16* qkv  = (bf16*)(ws + 8388608 + 1572864 + 524288);      // 25,165,824 B
  bf16* aout = (bf16*)(ws + 8388608 + 1572864 + 524288 + 25165824);  // 8,388,608 B

  cast_x_kernel<<<2048, 256, 0, stream>>>(x, xb);
  cast_w_kernel<<<512, 256, 0, stream>>>(Wq, Wk, Wv, Wp, wqkv, wpb);
  // QKV: M=8192, N=1536 -> 64 x 12 tiles
  gemm_bt_kernel<0><<<64 * 12, 256, 0, stream>>>(xb, wqkv, qkv, 1536, nullptr, nullptr, 12);
  // attn: blocks = B(2) * H(8) * T/TCB(64) = 1024
  attn_kernel<<<1024, 256, 0, stream>>>(qkv, aout);
  // proj + residual: M=8192, N=512 -> 64 x 4 tiles
  gemm_bt_kernel<1><<<64 * 4, 256, 0, stream>>>(aout, wpb, nullptr, 0, out, x, 4);
  ln_kernel<<<2048, 256, 0, stream>>>(out, g, be);
}

// Round 6
// 64.890 us; speedup vs baseline: 1.3154x; 1.0277x over previous
//
#include <hip/hip_runtime.h>
#include <hip/hip_bf16.h>
#include <stdint.h>

typedef __bf16 bf16;
typedef __attribute__((ext_vector_type(8))) __bf16 bf16x8;
typedef __attribute__((ext_vector_type(2))) __bf16 bf16x2;
typedef __attribute__((ext_vector_type(4))) float f32x4;
typedef __attribute__((ext_vector_type(4))) unsigned int u32x4;

#define GLOAD16(gsrc, ldst)                                              \
  __builtin_amdgcn_global_load_lds(                                      \
      (const __attribute__((address_space(1))) unsigned int*)(gsrc),     \
      (__attribute__((address_space(3))) unsigned int*)(ldst), 16, 0, 0)

static constexpr int T_LEN = 4096;
static constexpr int WIN = 16;

__device__ __forceinline__ bf16x8 cvt8(float4 a, float4 b) {
  bf16x8 o;
  o[0] = (bf16)a.x; o[1] = (bf16)a.y; o[2] = (bf16)a.z; o[3] = (bf16)a.w;
  o[4] = (bf16)b.x; o[5] = (bf16)b.y; o[6] = (bf16)b.z; o[7] = (bf16)b.w;
  return o;
}

// ---- fused casts: blocks 0..2047 -> x, 2048..2559 -> weights ----
__global__ __launch_bounds__(256) void prep_kernel(const float* __restrict__ x,
                                                   const float* __restrict__ wq,
                                                   const float* __restrict__ wk,
                                                   const float* __restrict__ wv,
                                                   const float* __restrict__ wp,
                                                   bf16* __restrict__ xb,
                                                   bf16* __restrict__ wqkv,
                                                   bf16* __restrict__ wpb) {
  int bid = blockIdx.x;
  if (bid < 2048) {
    int i = bid * 256 + threadIdx.x;  // 524288 threads, 8 elems each
    const float4* s4 = (const float4*)x + (size_t)i * 2;
    ((bf16x8*)xb)[i] = cvt8(s4[0], s4[1]);
  } else {
    int i = (bid - 2048) * 256 + threadIdx.x;  // 131072 threads
    int which = i >> 15;
    int j = i & 32767;
    const float* src = (which == 0) ? wq : (which == 1) ? wk : (which == 2) ? wv : wp;
    bf16* dst = (which < 3) ? (wqkv + (size_t)which * 512 * 512) : wpb;
    const float4* s4 = (const float4*)src + (size_t)j * 2;
    ((bf16x8*)dst)[j] = cvt8(s4[0], s4[1]);
  }
}

// ---- QKV GEMM: C[m][n] = sum_k A[m][k] * Bw[n][k], bf16 out, ldc=1536 ----
__global__ __launch_bounds__(256) void gemm_bt_kernel(const bf16* __restrict__ A,
                                                      const bf16* __restrict__ Bw,
                                                      bf16* __restrict__ Cb, int ldc,
                                                      int NB) {
  constexpr int K = 512, BK = 32;
  __shared__ __align__(16) bf16 As[128 * BK];
  __shared__ __align__(16) bf16 Bs[128 * BK];
  const int tid = threadIdx.x;
  const int l = tid & 63;
  const int w = tid >> 6;
  const int m0 = (blockIdx.x / NB) * 128;
  const int n0 = (blockIdx.x % NB) * 128;
  const int arow = tid >> 2;
  const int acol = (tid & 3) * 8;
  const bf16* Ag = A + (size_t)(m0 + arow) * K + acol;
  const bf16* Bg = Bw + (size_t)(n0 + arow) * K + acol;

  const f32x4 zero = {0.f, 0.f, 0.f, 0.f};
  f32x4 acc[4][4];
#pragma unroll
  for (int i = 0; i < 4; ++i)
#pragma unroll
    for (int j = 0; j < 4; ++j) acc[i][j] = zero;

  const int wm = (w >> 1) * 64;
  const int wn = (w & 1) * 64;
  const int frow = l & 15;
  const int fcol = (l >> 4) * 8;

  for (int k0 = 0; k0 < K; k0 += BK) {
    GLOAD16(Ag + k0,           &As[tid * 8]);
    GLOAD16(Ag + 64 * K + k0,  &As[tid * 8 + 2048]);
    GLOAD16(Bg + k0,           &Bs[tid * 8]);
    GLOAD16(Bg + 64 * K + k0,  &Bs[tid * 8 + 2048]);
    __syncthreads();
    bf16x8 af[4], bfr[4];
#pragma unroll
    for (int mi = 0; mi < 4; ++mi)
      af[mi] = *(const bf16x8*)&As[(wm + mi * 16 + frow) * BK + fcol];
#pragma unroll
    for (int ni = 0; ni < 4; ++ni)
      bfr[ni] = *(const bf16x8*)&Bs[(wn + ni * 16 + frow) * BK + fcol];
#pragma unroll
    for (int mi = 0; mi < 4; ++mi)
#pragma unroll
      for (int ni = 0; ni < 4; ++ni)
        acc[mi][ni] = __builtin_amdgcn_mfma_f32_16x16x32_bf16(af[mi], bfr[ni], acc[mi][ni], 0, 0, 0);
    __syncthreads();
  }

  const int r0 = (l >> 4) * 4;
  const int c0 = l & 15;
#pragma unroll
  for (int mi = 0; mi < 4; ++mi)
#pragma unroll
    for (int ni = 0; ni < 4; ++ni) {
      int row = m0 + wm + mi * 16 + r0;
      int col = n0 + wn + ni * 16 + c0;
#pragma unroll
      for (int r = 0; r < 4; ++r)
        Cb[(size_t)(row + r) * ldc + col] = (bf16)acc[mi][ni][r];
    }
}

// ---- local attention, MFMA-based, V staged transposed ----
static constexpr int TCB = 64;
static constexpr int NP = 96;
static constexpr int KST = 72;
static constexpr int NPT = 112;  // Vt col count (96 window + 16 zero halo)

__global__ __launch_bounds__(256) void attn_kernel(const bf16* __restrict__ qkv,
                                                   bf16* __restrict__ aout) {
  __shared__ __align__(16) bf16 Kl[NP * KST];
  __shared__ __align__(16) unsigned short Vt[64 * NPT];  // V^T[d][p]
  __shared__ __align__(16) bf16 PO[4 * 16 * 72];

  const int tid = threadIdx.x;
  const int wid = tid >> 6;
  const int l = tid & 63;
  const int g = l >> 4;
  const int c = l & 15;

  const int bid = blockIdx.x;  // 1024 = 2 * 8 * 64
  const int chunk = bid & 63;
  const int h = (bid >> 6) & 7;
  const int b = bid >> 9;
  const int t0 = chunk * TCB;
  const int base = b * T_LEN;

  // ---- stage K row-major, V transposed ----
#pragma unroll
  for (int i = 0; i < 3; ++i) {
    int task = tid + i * 256;  // 768 = 96 pos x 8 col-chunks
    int p = task >> 3;
    int c8 = (task & 7) * 8;
    int pg = min(max(t0 - WIN + p, 0), T_LEN - 1);
    const bf16* kr = qkv + (size_t)(base + pg) * 1536 + 512 + h * 64 + c8;
    const bf16* vr = qkv + (size_t)(base + pg) * 1536 + 1024 + h * 64 + c8;
    *(bf16x8*)&Kl[p * KST + c8] = *(const bf16x8*)kr;
    bf16x8 vv = *(const bf16x8*)vr;
#pragma unroll
    for (int e = 0; e < 8; ++e)
      Vt[(c8 + e) * NPT + p] = ((const unsigned short*)&vv)[e];
  }
  // zero-fill halo cols p=96..111 (read when wid=3,g>=2 where P=0; must be finite)
  {
    int d = tid >> 2;
    int p0 = 96 + (tid & 3) * 4;
    *(uint2*)&Vt[d * NPT + p0] = make_uint2(0u, 0u);
  }
  __syncthreads();

  const int tg = t0 + wid * 16;
  const float scale = 0.125f;  // 64^-0.5

  // ---- Q fragments: k-map (g,e) -> d = 32*kh + 8g + e ----
  const bf16* qrow = qkv + (size_t)(base + tg + c) * 1536 + h * 64;
  bf16x8 qf0 = *(const bf16x8*)(qrow + g * 8);
  bf16x8 qf1 = *(const bf16x8*)(qrow + 32 + g * 8);

  const f32x4 zero = {0.f, 0.f, 0.f, 0.f};
  const u32x4 zu = {0u, 0u, 0u, 0u};

  // ---- S^T = K @ Q^T ----
  f32x4 st[3];
#pragma unroll
  for (int wt = 0; wt < 3; ++wt) {
    int rk = 16 * wid + 16 * wt + c;
    bf16x8 ka0 = *(const bf16x8*)&Kl[rk * KST + g * 8];
    bf16x8 ka1 = *(const bf16x8*)&Kl[rk * KST + 32 + g * 8];
    f32x4 t = __builtin_amdgcn_mfma_f32_16x16x32_bf16(ka0, qf0, zero, 0, 0, 0);
    st[wt] = __builtin_amdgcn_mfma_f32_16x16x32_bf16(ka1, qf1, t, 0, 0, 0);
  }

  // ---- masked exp + row-sum (q=c; w = 16wt+4g+r) ----
  float pv[3][4];
  float lsum = 0.f;
#pragma unroll
  for (int wt = 0; wt < 3; ++wt)
#pragma unroll
    for (int r = 0; r < 4; ++r) {
      int w = 16 * wt + 4 * g + r;
      int pos = tg - WIN + w;
      bool valid = (w >= c) && (w <= c + 32) && (pos >= 0) && (pos < T_LEN);
      float e = __expf(st[wt][r] * scale);
      pv[wt][r] = valid ? e : 0.f;
      lsum += pv[wt][r];
    }
  lsum += __shfl_xor(lsum, 16);
  lsum += __shfl_xor(lsum, 32);
  float inv = 1.f / lsum;

  // ---- write normalized P (bf16, stride 56) ----
  bf16* P = &PO[wid * 16 * 72];
#pragma unroll
  for (int wt = 0; wt < 3; ++wt) {
    bf16x2 p01, p23;
    p01[0] = (bf16)(pv[wt][0] * inv);
    p01[1] = (bf16)(pv[wt][1] * inv);
    p23[0] = (bf16)(pv[wt][2] * inv);
    p23[1] = (bf16)(pv[wt][3] * inv);
    *(bf16x2*)&P[c * 56 + 16 * wt + 4 * g]     = p01;
    *(bf16x2*)&P[c * 56 + 16 * wt + 4 * g + 2] = p23;
  }

  // ---- PV: O[16q][64d] ----
  bf16x8 pa0 = *(const bf16x8*)&P[c * 56 + 8 * g];
  int g1 = (g < 2) ? g : 1;
  bf16x8 pa1 = *(const bf16x8*)&P[c * 56 + 32 + 8 * g1];
  if (g >= 2) pa1 = __builtin_bit_cast(bf16x8, zu);  // w>=48 -> P=0

  f32x4 acc[4] = {zero, zero, zero, zero};
#pragma unroll
  for (int dt = 0; dt < 4; ++dt) {
    const unsigned short* vp = &Vt[(16 * dt + c) * NPT + 16 * wid + 8 * g];
    bf16x8 v0 = *(const bf16x8*)(vp);        // kh0: w = 8g+e
    bf16x8 v1 = *(const bf16x8*)(vp + 32);   // kh1: w = 32+8g+e
    acc[dt] = __builtin_amdgcn_mfma_f32_16x16x32_bf16(pa0, v0, acc[dt], 0, 0, 0);
    acc[dt] = __builtin_amdgcn_mfma_f32_16x16x32_bf16(pa1, v1, acc[dt], 0, 0, 0);
  }

  // ---- O to LDS (stride 72), coalesced store ----
  bf16* O = &PO[wid * 16 * 72];
#pragma unroll
  for (int dt = 0; dt < 4; ++dt)
#pragma unroll
    for (int r = 0; r < 4; ++r)
      O[(4 * g + r) * 72 + 16 * dt + c] = (bf16)acc[dt][r];

  bf16x8 o0 = *(const bf16x8*)&O[c * 72 + g * 8];
  bf16x8 o1 = *(const bf16x8*)&O[c * 72 + 32 + g * 8];
  bf16* orow = aout + (size_t)(base + tg + c) * 512 + h * 64;
  *(bf16x8*)(orow + g * 8) = o0;
  *(bf16x8*)(orow + 32 + g * 8) = o1;
}

// ---- proj GEMM + residual + LayerNorm fused ----
// Block: 32 rows x full 512 cols, 512 threads (8 waves, each 32x64 out).
__global__ __launch_bounds__(512) void proj_ln_kernel(const bf16* __restrict__ A,
                                                      const bf16* __restrict__ Bw,
                                                      const float* __restrict__ X,
                                                      const float* __restrict__ gamma,
                                                      const float* __restrict__ beta,
                                                      float* __restrict__ out) {
  constexpr int K = 512, BK = 32, BM = 32;
  __shared__ __align__(16) bf16 As[BM * BK];      // 2 KB
  __shared__ __align__(16) bf16 Bs[512 * BK];     // 32 KB
  __shared__ __align__(16) float rsum[32][8];
  __shared__ __align__(16) float rsq[32][8];

  const int tid = threadIdx.x;
  const int w = tid >> 6;
  const int l = tid & 63;
  const int g = l >> 4;
  const int c = l & 15;
  const int m0 = blockIdx.x * BM;

  const f32x4 zero = {0.f, 0.f, 0.f, 0.f};
  f32x4 acc[2][4];
#pragma unroll
  for (int m = 0; m < 2; ++m)
#pragma unroll
    for (int n = 0; n < 4; ++n) acc[m][n] = zero;

  for (int k0 = 0; k0 < K; k0 += BK) {
    if (tid < 128)
      GLOAD16(A + (size_t)(m0 + (tid >> 2)) * K + k0 + (tid & 3) * 8, &As[tid * 8]);
#pragma unroll
    for (int j = 0; j < 4; ++j) {
      int tau = tid + 512 * j;
      GLOAD16(Bw + (size_t)(tau >> 2) * K + k0 + (tau & 3) * 8, &Bs[tau * 8]);
    }
    __syncthreads();
    bf16x8 af[2], bfv[4];
#pragma unroll
    for (int m = 0; m < 2; ++m)
      af[m] = *(const bf16x8*)&As[(m * 16 + c) * BK + 8 * g];
#pragma unroll
    for (int n = 0; n < 4; ++n)
      bfv[n] = *(const bf16x8*)&Bs[(w * 64 + n * 16 + c) * BK + 8 * g];
#pragma unroll
    for (int m = 0; m < 2; ++m)
#pragma unroll
      for (int n = 0; n < 4; ++n)
        acc[m][n] = __builtin_amdgcn_mfma_f32_16x16x32_bf16(af[m], bfv[n], acc[m][n], 0, 0, 0);
    __syncthreads();
  }

  // residual add + per-row partial sums (row = m*16 + 4g + r, col = w*64 + n*16 + c)
  const int col0 = w * 64 + c;
  float ps[2][4], ps2[2][4];
#pragma unroll
  for (int m = 0; m < 2; ++m)
#pragma unroll
    for (int r = 0; r < 4; ++r) {
      int row = m0 + m * 16 + 4 * g + r;
      float s = 0.f, s2 = 0.f;
#pragma unroll
      for (int n = 0; n < 4; ++n) {
        float y = acc[m][n][r] + X[(size_t)row * 512 + col0 + n * 16];
        acc[m][n][r] = y;
        s += y;
        s2 += y * y;
      }
      ps[m][r] = s;
      ps2[m][r] = s2;
    }
#pragma unroll
  for (int m = 0; m < 2; ++m)
#pragma unroll
    for (int r = 0; r < 4; ++r) {
      float s = ps[m][r], s2 = ps2[m][r];
      s += __shfl_xor(s, 1);  s2 += __shfl_xor(s2, 1);
      s += __shfl_xor(s, 2);  s2 += __shfl_xor(s2, 2);
      s += __shfl_xor(s, 4);  s2 += __shfl_xor(s2, 4);
      s += __shfl_xor(s, 8);  s2 += __shfl_xor(s2, 8);
      ps[m][r] = s;
      ps2[m][r] = s2;
    }
  if (c == 0) {
#pragma unroll
    for (int m = 0; m < 2; ++m)
#pragma unroll
      for (int r = 0; r < 4; ++r) {
        rsum[m * 16 + 4 * g + r][w] = ps[m][r];
        rsq[m * 16 + 4 * g + r][w] = ps2[m][r];
      }
  }
  __syncthreads();

  float gam[4], bet[4];
#pragma unroll
  for (int n = 0; n < 4; ++n) {
    gam[n] = gamma[col0 + n * 16];
    bet[n] = beta[col0 + n * 16];
  }
#pragma unroll
  for (int m = 0; m < 2; ++m)
#pragma unroll
    for (int r = 0; r < 4; ++r) {
      int rl = m * 16 + 4 * g + r;
      float4 s0 = *(const float4*)&rsum[rl][0];
      float4 s1 = *(const float4*)&rsum[rl][4];
      float4 q0 = *(const float4*)&rsq[rl][0];
      float4 q1 = *(const float4*)&rsq[rl][4];
      float sum = (s0.x + s0.y + s0.z + s0.w) + (s1.x + s1.y + s1.z + s1.w);
      float sq  = (q0.x + q0.y + q0.z + q0.w) + (q1.x + q1.y + q1.z + q1.w);
      float mu = sum * (1.f / 512.f);
      float var = sq * (1.f / 512.f) - mu * mu;
      float rs = rsqrtf(var + 1e-5f);
#pragma unroll
      for (int n = 0; n < 4; ++n)
        out[(size_t)(m0 + rl) * 512 + col0 + n * 16] =
            gam[n] * (acc[m][n][r] - mu) * rs + bet[n];
    }
}

extern "C" void kernel_launch(void* const* d_in, const int* in_sizes, int n_in,
                              void* d_out, int out_size, void* d_ws, size_t ws_size,
                              hipStream_t stream) {
  const float* x  = (const float*)d_in[0];
  const float* Wq = (const float*)d_in[1];
  const float* Wk = (const float*)d_in[2];
  const float* Wv = (const float*)d_in[3];
  const float* Wp = (const float*)d_in[4];
  const float* g  = (const float*)d_in[5];
  const float* be = (const float*)d_in[6];
  float* out = (float*)d_out;

  char* ws = (char*)d_ws;
  bf16* xb   = (bf16*)(ws);                                   // 8,388,608 B
  bf16* wqkv = (bf16*)(ws + 8388608);                         // 1,572,864 B
  bf16* wpb  = (bf16*)(ws + 8388608 + 1572864);               //   524,288 B
  bf16* qkv  = (bf16*)(ws + 8388608 + 1572864 + 524288);      // 25,165,824 B
  bf16* aout = (bf16*)(ws + 8388608 + 1572864 + 524288 + 25165824);  // 8,388,608 B

  prep_kernel<<<2560, 256, 0, stream>>>(x, Wq, Wk, Wv, Wp, xb, wqkv, wpb);
  // QKV: M=8192, N=1536 -> 64 x 12 tiles
  gemm_bt_kernel<<<64 * 12, 256, 0, stream>>>(xb, wqkv, qkv, 1536, 12);
  // attn: blocks = B(2) * H(8) * T/TCB(64) = 1024
  attn_kernel<<<1024, 256, 0, stream>>>(qkv, aout);
  // proj + residual + LN: 8192/32 = 256 blocks
  proj_ln_kernel<<<256, 512, 0, stream>>>(aout, wpb, x, g, be, out);
}